// Round 7
// baseline (381.286 us; speedup 1.0000x reference)
//
#include <hip/hip_runtime.h>
#include <hip/hip_cooperative_groups.h>

namespace cg = cooperative_groups;

#define N_IN   16384
#define N_OUT  16384
#define KSZ    9
#define CIN    32
#define COUT   32
#define BC     64
#define NCB    256         // coarse buckets = io >> 6  (64 n each)
#define CHA    4096        // bin chunk (round-0 proven)
#define ECAP_A 8192        // sivA region per coarse bucket (mean 5859)
#define GSTR   16          // gcnt stride in ints: one counter per 64B line
#define ROWS   144         // 9 k * 16 n per fine slice
#define XSTR   68          // sxk row stride: %32==4 -> max 4-way on b128, 16B-aligned
#define SCAP   2048        // slist cap per fine slice (mean 1465, +15 sigma)
#define NSLICE 1024        // fine output slices

struct BinSH { int cnt[NCB]; int cntE[NCB]; int gbase[NCB]; int cursor[NCB];
               float2 slist[CHA]; };                       // 36 KB
struct XqSH  { float tile[64 * 65]; };                     // 16.6 KB
struct FusSH { float sxk[80 * XSTR]; float2 slist[SCAP];
               int rowStart[ROWS + 1]; int cursor[ROWS]; int mcur; };  // 39.3 KB
union __align__(16) MegaSH { BinSH bin; XqSH xqp; FusSH fus; };

// ---------------------------------------------------------------------------
// k_mega: ONE cooperative launch replacing {memset, k_prep, k_fused6}
// (measured ~40us of the 147us total was inter-node launch overhead: round-0
// residue total-fused = 92.5us while prep itself never exceeds 54us).
// Phase 0: zero gcnt (line-padded: 94K device atomics spread over 256 L2
// lines instead of 16). Phase 1: round-0 prep verbatim. Phase 2: fused6
// verbatim, f = bid (round-6 measured: XCD swizzle cut FETCH 44->30MB but
// COST 21us via same-XCD L2 contention -> dropped).
__global__ __launch_bounds__(512, 8) void k_mega(
        const float* __restrict__ x, const float* __restrict__ qw,
        const float* __restrict__ vals, const float* __restrict__ w,
        const float* __restrict__ bias,
        const int* __restrict__ ik, const int* __restrict__ io,
        const int* __restrict__ ii, float* __restrict__ xq,
        float2* __restrict__ sivA, int* __restrict__ gcntA,
        float* __restrict__ wT, float* __restrict__ out,
        int nnz, int nchA) {
    __shared__ MegaSH sh;
    const int t    = threadIdx.x;
    const int lane = t & 63;
    const int wv   = __builtin_amdgcn_readfirstlane(t >> 6);

    // ---- phase 0: zero the padded global cursors
    if (blockIdx.x == 0 && t < NCB) gcntA[t * GSTR] = 0;
    cg::this_grid().sync();

    // ---- phase 1: binning + transposes (round-0 prep, work-item loop)
    for (int wk = blockIdx.x; wk < nchA + 257; wk += gridDim.x) {
        if (wk >= nchA) {
            if (wk < nchA + 256) {
                const int in0 = (wk - nchA) * 64;
#pragma unroll
                for (int i = 0; i < 8; ++i) {
                    int idx = t + i * 512;
                    int bcl = idx >> 6, inl = idx & 63;
                    sh.xqp.tile[bcl * 65 + inl] = x[bcl * N_IN + in0 + inl];
                }
                __syncthreads();
#pragma unroll
                for (int i = 0; i < 8; ++i) {
                    int idx = t + i * 512;
                    int inl = idx >> 6, bcl = idx & 63;
                    xq[(size_t)(in0 + inl) * BC + bcl] = sh.xqp.tile[bcl * 65 + inl] * qw[in0 + inl];
                }
                __syncthreads();
            } else {
                for (int i = t; i < COUT * CIN * KSZ; i += 512) {
                    int o = i / (CIN * KSZ);
                    int r = i - o * (CIN * KSZ);
                    int c = r / KSZ;
                    int k = r - c * KSZ;
                    wT[((k * 8 + (o >> 2)) * 32 + c) * 4 + (o & 3)] = w[i];
                }
            }
            continue;
        }
        // binning work item wk
        if (t < NCB) sh.bin.cnt[t] = 0;
        __syncthreads();
        const int base = wk * CHA;
        const int e0   = base + t * 8;

        float vv[8]; int pk[8]; int bk[8]; bool hv[8];
        if (e0 + 8 <= nnz) {
            int4 a0 = *(const int4*)(io + e0),  a1 = *(const int4*)(io + e0 + 4);
            int4 b0 = *(const int4*)(ii + e0),  b1 = *(const int4*)(ii + e0 + 4);
            int4 k0 = *(const int4*)(ik + e0),  k1 = *(const int4*)(ik + e0 + 4);
            float4 d0 = *(const float4*)(vals + e0), d1 = *(const float4*)(vals + e0 + 4);
            int ov[8] = {a0.x, a0.y, a0.z, a0.w, a1.x, a1.y, a1.z, a1.w};
            int iv[8] = {b0.x, b0.y, b0.z, b0.w, b1.x, b1.y, b1.z, b1.w};
            int kv[8] = {k0.x, k0.y, k0.z, k0.w, k1.x, k1.y, k1.z, k1.w};
            float dv[8] = {d0.x, d0.y, d0.z, d0.w, d1.x, d1.y, d1.z, d1.w};
#pragma unroll
            for (int j = 0; j < 8; ++j) {
                hv[j] = true;
                bk[j] = ov[j] >> 6;
                pk[j] = (int)(((unsigned)(ov[j] >> 4) << 22)) | (iv[j] << 8) | (kv[j] * 16 + (ov[j] & 15));
                vv[j] = dv[j];
            }
        } else {
#pragma unroll
            for (int j = 0; j < 8; ++j) {
                int e = e0 + j;
                hv[j] = (e < nnz);
                if (hv[j]) {
                    int o = io[e];
                    bk[j] = o >> 6;
                    pk[j] = (int)(((unsigned)(o >> 4) << 22)) | (ii[e] << 8) | (ik[e] * 16 + (o & 15));
                    vv[j] = vals[e];
                } else { bk[j] = 0; pk[j] = 0; vv[j] = 0.f; }
            }
        }
#pragma unroll
        for (int j = 0; j < 8; ++j) if (hv[j]) atomicAdd(&sh.bin.cnt[bk[j]], 1);
        __syncthreads();
        if (t < NCB) {
            int cv = sh.bin.cnt[t];
            sh.bin.gbase[t] = t * ECAP_A + (cv ? atomicAdd(&gcntA[t * GSTR], cv) : 0);
        }
        if (t < 64) {
            int carry = 0;
#pragma unroll
            for (int seg = 0; seg < 4; ++seg) {
                int idx = seg * 64 + t;
                int v = sh.bin.cnt[idx];
                int orig = v;
#pragma unroll
                for (int off = 1; off < 64; off <<= 1) {
                    int u = __shfl_up(v, off);
                    if (t >= off) v += u;
                }
                sh.bin.cntE[idx]   = carry + v - orig;
                sh.bin.cursor[idx] = carry + v - orig;
                carry += __shfl(v, 63);
            }
        }
        __syncthreads();
#pragma unroll
        for (int j = 0; j < 8; ++j) {
            if (hv[j]) {
                int pos = atomicAdd(&sh.bin.cursor[bk[j]], 1);
                sh.bin.slist[pos] = make_float2(vv[j], __int_as_float(pk[j]));
            }
        }
        __syncthreads();
        const int m = min(nnz - base, CHA);
        for (int p = t; p < m; p += 512) {
            float2 f2 = sh.bin.slist[p];
            int cb = (int)((unsigned)__float_as_int(f2.y) >> 24);
            int dest = sh.bin.gbase[cb] + (p - sh.bin.cntE[cb]);
            if (dest < (cb + 1) * ECAP_A) sivA[dest] = f2;
        }
        __syncthreads();
    }

    cg::this_grid().sync();

    // ---- phase 2: fused6 verbatim (f = bid, no swizzle)
    for (unsigned f = blockIdx.x; f < NSLICE; f += gridDim.x) {
        if (t < ROWS) sh.fus.rowStart[t] = 0;
        if (t == 0) sh.fus.mcur = 0;
        __syncthreads();

        const int cb = (int)(f >> 2);
        const int mA = min(gcntA[cb * GSTR], ECAP_A);
        const float2* src = sivA + (size_t)cb * ECAP_A;
        float2* tmp = (float2*)sh.fus.sxk;
        for (int i = t; i < mA; i += 512) {
            float2 v = src[i];
            unsigned fid = (unsigned)__float_as_int(v.y) >> 22;
            if (fid == f) {
                int pos = atomicAdd(&sh.fus.mcur, 1);
                if (pos < SCAP) {
                    tmp[pos] = v;
                    atomicAdd(&sh.fus.rowStart[__float_as_int(v.y) & 0xFF], 1);
                }
            }
        }
        __syncthreads();
        const int m2 = min(sh.fus.mcur, SCAP);
        if (wv == 0) {   // exclusive scan over 144 counts
            int carry = 0;
#pragma unroll
            for (int i0 = 0; i0 < 192; i0 += 64) {
                int idx = i0 + lane;
                int v = (idx < ROWS) ? sh.fus.rowStart[idx] : 0;
                int orig = v;
#pragma unroll
                for (int off = 1; off < 64; off <<= 1) {
                    int u = __shfl_up(v, off);
                    if (lane >= off) v += u;
                }
                if (idx < ROWS) {
                    int excl = carry + v - orig;
                    sh.fus.rowStart[idx] = excl;
                    sh.fus.cursor[idx]   = excl;
                }
                carry += __shfl(v, 63);
            }
            if (lane == 0) sh.fus.rowStart[ROWS] = carry;
        }
        __syncthreads();
        for (int i = t; i < m2; i += 512) {
            float2 v = tmp[i];
            int p = __float_as_int(v.y);
            int pos = atomicAdd(&sh.fus.cursor[p & 0xFF], 1);
            sh.fus.slist[pos] = make_float2(v.x, __int_as_float(p & 0x3FFF00));
        }
        __syncthreads();   // tmp reads complete before sxk zeroing

        const char* xqb   = (const char*)xq;
        const int   lane4 = lane * 4;
        const int   h     = lane >> 4;
        const int   nl    = lane & 15;
        float acc[4] = {0.f, 0.f, 0.f, 0.f};

#pragma unroll
        for (int ph = 0; ph < 2; ++ph) {
            const int rbase = ph ? 80 : 0;
            const int rend  = ph ? 144 : 80;
            const int nrows = rend - rbase;
            for (int i = t; i < nrows * XSTR; i += 512) sh.fus.sxk[i] = 0.f;
            __syncthreads();
            for (int r = rbase + wv; r < rend; r += 8) {
                const int a = sh.fus.rowStart[r], b = sh.fus.rowStart[r + 1];
                if (a >= b) continue;
                float acc0 = 0.f, acc1 = 0.f, acc2 = 0.f, acc3 = 0.f;
                int i = a;
                for (; i + 7 < b; i += 8) {
                    float2 v0 = sh.fus.slist[i],     v1 = sh.fus.slist[i + 1];
                    float2 v2 = sh.fus.slist[i + 2], v3 = sh.fus.slist[i + 3];
                    float2 v4 = sh.fus.slist[i + 4], v5 = sh.fus.slist[i + 5];
                    float2 v6 = sh.fus.slist[i + 6], v7 = sh.fus.slist[i + 7];
                    acc0 += *(const float*)(xqb + (__float_as_int(v0.y) + lane4)) * v0.x;
                    acc1 += *(const float*)(xqb + (__float_as_int(v1.y) + lane4)) * v1.x;
                    acc2 += *(const float*)(xqb + (__float_as_int(v2.y) + lane4)) * v2.x;
                    acc3 += *(const float*)(xqb + (__float_as_int(v3.y) + lane4)) * v3.x;
                    acc0 += *(const float*)(xqb + (__float_as_int(v4.y) + lane4)) * v4.x;
                    acc1 += *(const float*)(xqb + (__float_as_int(v5.y) + lane4)) * v5.x;
                    acc2 += *(const float*)(xqb + (__float_as_int(v6.y) + lane4)) * v6.x;
                    acc3 += *(const float*)(xqb + (__float_as_int(v7.y) + lane4)) * v7.x;
                }
                for (; i + 3 < b; i += 4) {
                    float2 v0 = sh.fus.slist[i],     v1 = sh.fus.slist[i + 1];
                    float2 v2 = sh.fus.slist[i + 2], v3 = sh.fus.slist[i + 3];
                    acc0 += *(const float*)(xqb + (__float_as_int(v0.y) + lane4)) * v0.x;
                    acc1 += *(const float*)(xqb + (__float_as_int(v1.y) + lane4)) * v1.x;
                    acc2 += *(const float*)(xqb + (__float_as_int(v2.y) + lane4)) * v2.x;
                    acc3 += *(const float*)(xqb + (__float_as_int(v3.y) + lane4)) * v3.x;
                }
                for (; i < b; ++i) {
                    float2 v = sh.fus.slist[i];
                    acc0 += *(const float*)(xqb + (__float_as_int(v.y) + lane4)) * v.x;
                }
                sh.fus.sxk[(r - rbase) * XSTR + lane] = (acc0 + acc1) + (acc2 + acc3);
            }
            __syncthreads();
            if (lane < 32) {
                const int kbase = ph ? 5 : 0;
                const int kcnt  = ph ? 4 : 5;
                for (int kk = 0; kk < kcnt; ++kk) {
                    const float* xr = &sh.fus.sxk[(kk * 16 + nl) * XSTR + h * 32];
                    const float* wp = &wT[((kbase + kk) * 8 + wv) * 128];   // uniform -> s_load
#pragma unroll
                    for (int c4 = 0; c4 < 8; ++c4) {
                        float4 xv = *(const float4*)&xr[c4 * 4];
#pragma unroll
                        for (int cc = 0; cc < 4; ++cc) {
                            float xval = (&xv.x)[cc];
#pragma unroll
                            for (int j = 0; j < 4; ++j)
                                acc[j] += xval * wp[(c4 * 4 + cc) * 4 + j];
                        }
                    }
                }
            }
            __syncthreads();
        }

        if (lane < 32) {
            const int n0 = (int)f * 16;
#pragma unroll
            for (int j = 0; j < 4; ++j) {
                int o = wv * 4 + j;
                out[((size_t)h * COUT + o) * N_OUT + n0 + nl] = acc[j] + bias[o];
            }
        }
        __syncthreads();   // slist/rowStart reuse on next f
    }
}

// ---------------------------------------------------------------------------
extern "C" void kernel_launch(void* const* d_in, const int* in_sizes, int n_in,
                              void* d_out, int out_size, void* d_ws, size_t ws_size,
                              hipStream_t stream) {
    const float* x    = (const float*)d_in[0];
    const float* qw   = (const float*)d_in[1];
    const float* vals = (const float*)d_in[2];
    const float* w    = (const float*)d_in[3];
    const float* bias = (const float*)d_in[4];
    const int*   ik   = (const int*)d_in[5];
    const int*   io   = (const int*)d_in[6];
    const int*   ii   = (const int*)d_in[7];
    int          nnz  = in_sizes[2];
    int          nchA = (nnz + CHA - 1) / CHA;

    char* ws = (char*)d_ws;
    float*  xq    = (float*)ws;  ws += (size_t)N_IN * BC * 4;        // 4 MB
    float2* sivA  = (float2*)ws; ws += (size_t)NCB * ECAP_A * 8;     // 16.78 MB
    int*    gcntA = (int*)ws;    ws += (size_t)NCB * GSTR * 4;       // 16 KB
    float*  wT    = (float*)ws;  ws += (size_t)COUT * CIN * KSZ * 4;
    float*  out   = (float*)d_out;

    static int nblk = 0;
    if (nblk == 0) {
        int occ = 0;
        if (hipOccupancyMaxActiveBlocksPerMultiprocessor(&occ, (const void*)k_mega,
                                                         512, 0) != hipSuccess || occ < 1)
            occ = 1;
        nblk = (occ >= 4) ? 1024 : (occ >= 2 ? 512 : 256);   // keep phase-2 balanced
    }

    void* args[] = { (void*)&x, (void*)&qw, (void*)&vals, (void*)&w, (void*)&bias,
                     (void*)&ik, (void*)&io, (void*)&ii, (void*)&xq, (void*)&sivA,
                     (void*)&gcntA, (void*)&wT, (void*)&out, (void*)&nnz, (void*)&nchA };
    hipLaunchCooperativeKernel((const void*)k_mega, dim3(nblk), dim3(512),
                               args, 0, stream);
}

// Round 9
// 151.337 us; speedup vs baseline: 2.5195x; 2.5195x over previous
//
#include <hip/hip_runtime.h>

#define N_IN   16384
#define N_OUT  16384
#define KSZ    9
#define CIN    32
#define COUT   32
#define BC     64
#define NCB    256         // coarse buckets = io >> 6  (64 n each)
#define CHA    4096        // bin chunk
#define ECAP_A 8192        // sivA region per coarse bucket (mean 5859)
#define ROWS   144         // 9 k * 16 n per fine slice
#define XSTR   68          // sxk row stride: %32==4 -> max 4-way on b128, 16B-aligned
#define SCAP   2048        // slist cap per fine slice (mean 1465, +15 sigma)

union PrepSH {
    struct { int cnt[NCB]; int cntE[NCB]; int gbase[NCB]; int cursor[NCB];
             float2 slist[CHA]; } bin;                 // 36 KB
    struct { float tile[64 * 65]; } xqp;               // 16.6 KB
};

// ---------------------------------------------------------------------------
// k_prep (round-0 verbatim, measured best of 4 prep variants tried in rounds
// 1-3): blocks [0,nchA) bin entries into 256 coarse buckets (LDS-staged,
// coalesced 128B-run flush); blocks [nchA, nchA+256) transpose x into xq;
// block nchA+256 transposes w. payload = (io>>4)<<22 | in<<8 | (k*16+(io&15)).
__global__ __launch_bounds__(512) void k_prep(
        const float* __restrict__ x, const float* __restrict__ qw,
        const float* __restrict__ vals, const float* __restrict__ w,
        const int* __restrict__ ik, const int* __restrict__ io,
        const int* __restrict__ ii, float* __restrict__ xq,
        float2* __restrict__ sivA, int* __restrict__ gcntA,
        float* __restrict__ wT, int nnz, int nchA) {
    __shared__ PrepSH sh;
    const int t = threadIdx.x;
    const int bid = blockIdx.x;

    if (bid >= nchA) {
        if (bid < nchA + 256) {
            const int in0 = (bid - nchA) * 64;
#pragma unroll
            for (int i = 0; i < 8; ++i) {
                int idx = t + i * 512;
                int bcl = idx >> 6, inl = idx & 63;
                sh.xqp.tile[bcl * 65 + inl] = x[bcl * N_IN + in0 + inl];
            }
            __syncthreads();
#pragma unroll
            for (int i = 0; i < 8; ++i) {
                int idx = t + i * 512;
                int inl = idx >> 6, bcl = idx & 63;
                xq[(size_t)(in0 + inl) * BC + bcl] = sh.xqp.tile[bcl * 65 + inl] * qw[in0 + inl];
            }
        } else {
            for (int i = t; i < COUT * CIN * KSZ; i += 512) {
                int o = i / (CIN * KSZ);
                int r = i - o * (CIN * KSZ);
                int c = r / KSZ;
                int k = r - c * KSZ;
                wT[((k * 8 + (o >> 2)) * 32 + c) * 4 + (o & 3)] = w[i];
            }
        }
        return;
    }

    // ---- binning block
    if (t < NCB) sh.bin.cnt[t] = 0;
    __syncthreads();
    const int base = bid * CHA;
    const int e0   = base + t * 8;

    float vv[8]; int pk[8]; int bk[8]; bool hv[8];
    if (e0 + 8 <= nnz) {
        int4 a0 = *(const int4*)(io + e0),  a1 = *(const int4*)(io + e0 + 4);
        int4 b0 = *(const int4*)(ii + e0),  b1 = *(const int4*)(ii + e0 + 4);
        int4 k0 = *(const int4*)(ik + e0),  k1 = *(const int4*)(ik + e0 + 4);
        float4 d0 = *(const float4*)(vals + e0), d1 = *(const float4*)(vals + e0 + 4);
        int ov[8] = {a0.x, a0.y, a0.z, a0.w, a1.x, a1.y, a1.z, a1.w};
        int iv[8] = {b0.x, b0.y, b0.z, b0.w, b1.x, b1.y, b1.z, b1.w};
        int kv[8] = {k0.x, k0.y, k0.z, k0.w, k1.x, k1.y, k1.z, k1.w};
        float dv[8] = {d0.x, d0.y, d0.z, d0.w, d1.x, d1.y, d1.z, d1.w};
#pragma unroll
        for (int j = 0; j < 8; ++j) {
            hv[j] = true;
            bk[j] = ov[j] >> 6;
            pk[j] = (int)(((unsigned)(ov[j] >> 4) << 22)) | (iv[j] << 8) | (kv[j] * 16 + (ov[j] & 15));
            vv[j] = dv[j];
        }
    } else {
#pragma unroll
        for (int j = 0; j < 8; ++j) {
            int e = e0 + j;
            hv[j] = (e < nnz);
            if (hv[j]) {
                int o = io[e];
                bk[j] = o >> 6;
                pk[j] = (int)(((unsigned)(o >> 4) << 22)) | (ii[e] << 8) | (ik[e] * 16 + (o & 15));
                vv[j] = vals[e];
            } else { bk[j] = 0; pk[j] = 0; vv[j] = 0.f; }
        }
    }
#pragma unroll
    for (int j = 0; j < 8; ++j) if (hv[j]) atomicAdd(&sh.bin.cnt[bk[j]], 1);
    __syncthreads();
    if (t < NCB) {
        int cv = sh.bin.cnt[t];
        sh.bin.gbase[t] = t * ECAP_A + (cv ? atomicAdd(&gcntA[t], cv) : 0);
    }
    if (t < 64) {
        int carry = 0;
#pragma unroll
        for (int seg = 0; seg < 4; ++seg) {
            int idx = seg * 64 + t;
            int v = sh.bin.cnt[idx];
            int orig = v;
#pragma unroll
            for (int off = 1; off < 64; off <<= 1) {
                int u = __shfl_up(v, off);
                if (t >= off) v += u;
            }
            sh.bin.cntE[idx]   = carry + v - orig;
            sh.bin.cursor[idx] = carry + v - orig;
            carry += __shfl(v, 63);
        }
    }
    __syncthreads();
#pragma unroll
    for (int j = 0; j < 8; ++j) {
        if (hv[j]) {
            int pos = atomicAdd(&sh.bin.cursor[bk[j]], 1);
            sh.bin.slist[pos] = make_float2(vv[j], __int_as_float(pk[j]));
        }
    }
    __syncthreads();
    const int m = min(nnz - base, CHA);
    for (int p = t; p < m; p += 512) {
        float2 f2 = sh.bin.slist[p];
        int cb = (int)((unsigned)__float_as_int(f2.y) >> 24);
        int dest = sh.bin.gbase[cb] + (p - sh.bin.cntE[cb]);
        if (dest < (cb + 1) * ECAP_A) sivA[dest] = f2;
    }
}

// ---------------------------------------------------------------------------
// k_fused6 (round-0 verbatim; reproduced at 54.3-54.8us in rounds 0/4/6):
// block = fine slice f (16 n). Single filter pass over coarse bucket f>>2
// into LDS tmp (aliased on sxk) + row counts; scan; LDS->LDS scatter
// (payload stripped to byte offset); per-wave register accumulation;
// half-wave einsum with wave-uniform weight pointers (s_load).
// Structural alternatives measured and rejected: fine-bucket front-ends
// (+14us), producer/consumer wave split (+29us), XCD swizzle (+21us despite
// FETCH 44->30MB), cooperative single-kernel fusion (+182us).
__global__ __launch_bounds__(512) void k_fused6(const float* __restrict__ xq,
        const float2* __restrict__ sivA, const int* __restrict__ gcntA,
        const float* __restrict__ wT, const float* __restrict__ bias,
        float* __restrict__ out) {
    __shared__ __align__(16) float sxk[80 * XSTR];   // 21760 B (>= SCAP*8 for tmp)
    __shared__ float2 slist[SCAP];                   // 16384 B
    __shared__ int    rowStart[ROWS + 1];
    __shared__ int    cursor[ROWS];
    __shared__ int    mcur;
    const int tid  = threadIdx.x;
    const int lane = tid & 63;
    const int wv   = __builtin_amdgcn_readfirstlane(tid >> 6);
    const unsigned f = blockIdx.x;

    if (tid < ROWS) rowStart[tid] = 0;
    if (tid == 0) mcur = 0;
    __syncthreads();

    const int cb = (int)(f >> 2);
    const int mA = min(gcntA[cb], ECAP_A);
    const float2* src = sivA + (size_t)cb * ECAP_A;
    float2* tmp = (float2*)sxk;
    for (int i = tid; i < mA; i += 512) {
        float2 v = src[i];
        unsigned fid = (unsigned)__float_as_int(v.y) >> 22;
        if (fid == f) {
            int pos = atomicAdd(&mcur, 1);
            if (pos < SCAP) {
                tmp[pos] = v;
                atomicAdd(&rowStart[__float_as_int(v.y) & 0xFF], 1);
            }
        }
    }
    __syncthreads();
    const int m2 = min(mcur, SCAP);
    if (wv == 0) {   // exclusive scan over 144 counts
        int carry = 0;
#pragma unroll
        for (int i0 = 0; i0 < 192; i0 += 64) {
            int idx = i0 + lane;
            int v = (idx < ROWS) ? rowStart[idx] : 0;
            int orig = v;
#pragma unroll
            for (int off = 1; off < 64; off <<= 1) {
                int u = __shfl_up(v, off);
                if (lane >= off) v += u;
            }
            if (idx < ROWS) {
                int excl = carry + v - orig;
                rowStart[idx] = excl;
                cursor[idx]   = excl;
            }
            carry += __shfl(v, 63);
        }
        if (lane == 0) rowStart[ROWS] = carry;
    }
    __syncthreads();
    // LDS->LDS scatter; strip row bits so gather needs only v_add
    for (int i = tid; i < m2; i += 512) {
        float2 v = tmp[i];
        int p = __float_as_int(v.y);
        int pos = atomicAdd(&cursor[p & 0xFF], 1);
        slist[pos] = make_float2(v.x, __int_as_float(p & 0x3FFF00));
    }
    __syncthreads();   // tmp reads complete before sxk zeroing

    const char* xqb   = (const char*)xq;
    const int   lane4 = lane * 4;
    const int   h     = lane >> 4;
    const int   nl    = lane & 15;
    float acc[4] = {0.f, 0.f, 0.f, 0.f};

#pragma unroll
    for (int ph = 0; ph < 2; ++ph) {
        const int rbase = ph ? 80 : 0;
        const int rend  = ph ? 144 : 80;
        const int nrows = rend - rbase;
        for (int i = tid; i < nrows * XSTR; i += 512) sxk[i] = 0.f;
        __syncthreads();
        for (int r = rbase + wv; r < rend; r += 8) {
            const int a = rowStart[r], b = rowStart[r + 1];
            if (a >= b) continue;
            float acc0 = 0.f, acc1 = 0.f, acc2 = 0.f, acc3 = 0.f;
            int i = a;
            for (; i + 7 < b; i += 8) {
                float2 v0 = slist[i],     v1 = slist[i + 1], v2 = slist[i + 2], v3 = slist[i + 3];
                float2 v4 = slist[i + 4], v5 = slist[i + 5], v6 = slist[i + 6], v7 = slist[i + 7];
                acc0 += *(const float*)(xqb + (__float_as_int(v0.y) + lane4)) * v0.x;
                acc1 += *(const float*)(xqb + (__float_as_int(v1.y) + lane4)) * v1.x;
                acc2 += *(const float*)(xqb + (__float_as_int(v2.y) + lane4)) * v2.x;
                acc3 += *(const float*)(xqb + (__float_as_int(v3.y) + lane4)) * v3.x;
                acc0 += *(const float*)(xqb + (__float_as_int(v4.y) + lane4)) * v4.x;
                acc1 += *(const float*)(xqb + (__float_as_int(v5.y) + lane4)) * v5.x;
                acc2 += *(const float*)(xqb + (__float_as_int(v6.y) + lane4)) * v6.x;
                acc3 += *(const float*)(xqb + (__float_as_int(v7.y) + lane4)) * v7.x;
            }
            for (; i + 3 < b; i += 4) {
                float2 v0 = slist[i], v1 = slist[i + 1], v2 = slist[i + 2], v3 = slist[i + 3];
                acc0 += *(const float*)(xqb + (__float_as_int(v0.y) + lane4)) * v0.x;
                acc1 += *(const float*)(xqb + (__float_as_int(v1.y) + lane4)) * v1.x;
                acc2 += *(const float*)(xqb + (__float_as_int(v2.y) + lane4)) * v2.x;
                acc3 += *(const float*)(xqb + (__float_as_int(v3.y) + lane4)) * v3.x;
            }
            for (; i < b; ++i) {
                float2 v = slist[i];
                acc0 += *(const float*)(xqb + (__float_as_int(v.y) + lane4)) * v.x;
            }
            sxk[(r - rbase) * XSTR + lane] = (acc0 + acc1) + (acc2 + acc3);
        }
        __syncthreads();
        if (lane < 32) {
            const int kbase = ph ? 5 : 0;
            const int kcnt  = ph ? 4 : 5;
            for (int kk = 0; kk < kcnt; ++kk) {
                const float* xr = &sxk[(kk * 16 + nl) * XSTR + h * 32];
                const float* wp = &wT[((kbase + kk) * 8 + wv) * 128];   // uniform -> s_load
#pragma unroll
                for (int c4 = 0; c4 < 8; ++c4) {
                    float4 xv = *(const float4*)&xr[c4 * 4];
#pragma unroll
                    for (int cc = 0; cc < 4; ++cc) {
                        float xval = (&xv.x)[cc];
#pragma unroll
                        for (int j = 0; j < 4; ++j)
                            acc[j] += xval * wp[(c4 * 4 + cc) * 4 + j];
                    }
                }
            }
        }
        __syncthreads();
    }

    if (lane < 32) {
        const int n0 = (int)f * 16;
#pragma unroll
        for (int j = 0; j < 4; ++j) {
            int o = wv * 4 + j;
            out[((size_t)h * COUT + o) * N_OUT + n0 + nl] = acc[j] + bias[o];
        }
    }
}

// ---------------------------------------------------------------------------
extern "C" void kernel_launch(void* const* d_in, const int* in_sizes, int n_in,
                              void* d_out, int out_size, void* d_ws, size_t ws_size,
                              hipStream_t stream) {
    const float* x    = (const float*)d_in[0];
    const float* qw   = (const float*)d_in[1];
    const float* vals = (const float*)d_in[2];
    const float* w    = (const float*)d_in[3];
    const float* bias = (const float*)d_in[4];
    const int*   ik   = (const int*)d_in[5];
    const int*   io   = (const int*)d_in[6];
    const int*   ii   = (const int*)d_in[7];
    const int    nnz  = in_sizes[2];
    const int    nchA = (nnz + CHA - 1) / CHA;

    char* ws = (char*)d_ws;
    float*  xq    = (float*)ws;  ws += (size_t)N_IN * BC * 4;        // 4 MB
    float2* sivA  = (float2*)ws; ws += (size_t)NCB * ECAP_A * 8;     // 16.78 MB
    int*    gcntA = (int*)ws;    ws += NCB * 4;
    float*  wT    = (float*)ws;  ws += (size_t)COUT * CIN * KSZ * 4;

    hipMemsetAsync(gcntA, 0, NCB * sizeof(int), stream);
    k_prep  <<<nchA + 257, 512, 0, stream>>>(x, qw, vals, w, ik, io, ii,
                                             xq, sivA, gcntA, wT, nnz, nchA);
    k_fused6<<<1024, 512, 0, stream>>>(xq, sivA, gcntA, wT, bias, (float*)d_out);
}